// Round 10
// baseline (572.463 us; speedup 1.0000x reference)
//
#include <hip/hip_runtime.h>
#include <math.h>

#define NN 20000
#define CC 512

__device__ __forceinline__ float eluf(float x) { return x > 0.f ? x : __expf(x) - 1.f; }

// ---------------- zero ----------------
__global__ void k_zero(float4* __restrict__ p, int n4) {
  int i = blockIdx.x * blockDim.x + threadIdx.x;
  if (i < n4) p[i] = make_float4(0.f, 0.f, 0.f, 0.f);
}

// ---------------- fused CSR counting (fine dst, coarse dst, cluster) ----------------
__global__ void k_count3(const int* __restrict__ dstF, int nF, int* __restrict__ cF,
                         const int* __restrict__ dstC, int nC, int* __restrict__ cC,
                         const int* __restrict__ clus, int nK, int* __restrict__ cK) {
  int i = blockIdx.x * blockDim.x + threadIdx.x;
  if (i < nF) { atomicAdd(&cF[dstF[i]], 1); return; }
  i -= nF;
  if (i < nC) { atomicAdd(&cC[dstC[i]], 1); return; }
  i -= nC;
  if (i < nK) atomicAdd(&cK[clus[i]], 1);
}

// ---------------- 3-array scan (block per array) + optional dinv ----------------
__global__ __launch_bounds__(1024) void k_scan3(
    const int* __restrict__ c0, int n0, int* __restrict__ r0, float* __restrict__ d0,
    const int* __restrict__ c1, int n1, int* __restrict__ r1, float* __restrict__ d1,
    const int* __restrict__ c2, int n2, int* __restrict__ r2) {
  const int* counts; int n; int* rowptr; float* dinv;
  if (blockIdx.x == 0) { counts = c0; n = n0; rowptr = r0; dinv = d0; }
  else if (blockIdx.x == 1) { counts = c1; n = n1; rowptr = r1; dinv = d1; }
  else { counts = c2; n = n2; rowptr = r2; dinv = nullptr; }
  __shared__ int part[1024];
  int tid = threadIdx.x;
  int chunk = (n + 1023) >> 10;
  int beg = tid * chunk;
  int fin = beg + chunk; if (fin > n) fin = n;
  int s = 0;
  for (int i = beg; i < fin; ++i) {
    int c = counts[i];
    s += c;
    if (dinv) dinv[i] = rsqrtf((float)(c + 1));  // +1 self-loop
  }
  part[tid] = s;
  __syncthreads();
  for (int off = 1; off < 1024; off <<= 1) {
    int v = (tid >= off) ? part[tid - off] : 0;
    __syncthreads();
    part[tid] += v;
    __syncthreads();
  }
  int base = (tid == 0) ? 0 : part[tid - 1];
  for (int i = beg; i < fin; ++i) { rowptr[i] = base; base += counts[i]; }
  if (tid == 1023) rowptr[n] = part[1023];
}

// ---------------- fused scatter (fine edges, coarse edges, cluster nodes) ----------------
__global__ void k_scatter3(
    const int* __restrict__ edgeF, int EF, const int* __restrict__ rowF, int* __restrict__ fillF,
    const float* __restrict__ dinvF, int* __restrict__ csrcF, float* __restrict__ cnormF,
    const int* __restrict__ edgeC, int EC, const int* __restrict__ rowC, int* __restrict__ fillC,
    const float* __restrict__ dinvC, int* __restrict__ csrcC, float* __restrict__ cnormC,
    const int* __restrict__ clus, int NK, const int* __restrict__ rowK, int* __restrict__ fillK,
    int* __restrict__ cnodes) {
  int i = blockIdx.x * blockDim.x + threadIdx.x;
  if (i < EF) {
    int d = edgeF[EF + i];
    int pos = rowF[d] + atomicAdd(&fillF[d], 1);
    int s = edgeF[i];
    csrcF[pos] = s;
    cnormF[pos] = dinvF[s] * dinvF[d];
    return;
  }
  i -= EF;
  if (i < EC) {
    int d = edgeC[EC + i];
    int pos = rowC[d] + atomicAdd(&fillC[d], 1);
    int s = edgeC[i];
    csrcC[pos] = s;
    cnormC[pos] = dinvC[s] * dinvC[d];
    return;
  }
  i -= EC;
  if (i < NK) {
    int d = clus[i];
    int pos = rowK[d] + atomicAdd(&fillK[d], 1);
    cnodes[pos] = i;
  }
}

// ---------------- big GEMM (fine, outF=64): 128x64 tile, BK=32, 8x4/thread ----------------
__global__ __launch_bounds__(256) void k_gemm2(const float* __restrict__ X,
                                               const float* __restrict__ W,
                                               const float* __restrict__ bias,
                                               float* __restrict__ Y,
                                               int nrows, int K, int outF, int act) {
  __shared__ float Xt[32][132];
  __shared__ float Wt[32][68];
  int row0 = blockIdx.x * 128;
  int col0 = blockIdx.y * 64;
  int tid = threadIdx.x;
  int tc = (tid & 15) * 4;
  int tr = (tid >> 4) * 8;
  float acc[8][4] = {};
  for (int kk = 0; kk < K; kk += 32) {
#pragma unroll
    for (int i = 0; i < 4; ++i) {
      int f = tid + 256 * i;        // 0..1023
      int r = f >> 3;               // 0..127
      int kq = f & 7;
      int gr = row0 + r;
      float4 v = make_float4(0.f, 0.f, 0.f, 0.f);
      if (gr < nrows) v = *(const float4*)&X[(size_t)gr * K + kk + kq * 4];
      int kb = kq * 4;
      Xt[kb][r] = v.x; Xt[kb + 1][r] = v.y; Xt[kb + 2][r] = v.z; Xt[kb + 3][r] = v.w;
    }
#pragma unroll
    for (int i = 0; i < 2; ++i) {
      int f = tid + 256 * i;        // 0..511
      int c = f >> 3;               // 0..63
      int kq = f & 7;
      int gc = col0 + c;
      float4 v = make_float4(0.f, 0.f, 0.f, 0.f);
      if (gc < outF) v = *(const float4*)&W[(size_t)gc * K + kk + kq * 4];
      int kb = kq * 4;
      Wt[kb][c] = v.x; Wt[kb + 1][c] = v.y; Wt[kb + 2][c] = v.z; Wt[kb + 3][c] = v.w;
    }
    __syncthreads();
#pragma unroll 8
    for (int k = 0; k < 32; ++k) {
      float4 w = *(const float4*)&Wt[k][tc];
      float4 xa = *(const float4*)&Xt[k][tr];
      float4 xb = *(const float4*)&Xt[k][tr + 4];
      float xs[8] = {xa.x, xa.y, xa.z, xa.w, xb.x, xb.y, xb.z, xb.w};
      float ws4[4] = {w.x, w.y, w.z, w.w};
#pragma unroll
      for (int i = 0; i < 8; ++i)
#pragma unroll
        for (int j = 0; j < 4; ++j) acc[i][j] += xs[i] * ws4[j];
    }
    __syncthreads();
  }
#pragma unroll
  for (int i = 0; i < 8; ++i) {
    int gr = row0 + tr + i;
    if (gr >= nrows) continue;
    int gc = col0 + tc;
    float4 v;
    v.x = acc[i][0]; v.y = acc[i][1]; v.z = acc[i][2]; v.w = acc[i][3];
    if (bias) { v.x += bias[gc]; v.y += bias[gc + 1]; v.z += bias[gc + 2]; v.w += bias[gc + 3]; }
    if (act) { v.x = eluf(v.x); v.y = eluf(v.y); v.z = eluf(v.z); v.w = eluf(v.w); }
    if (gc + 3 < outF) {
      *(float4*)&Y[(size_t)gr * outF + gc] = v;
    } else {
      float vs[4] = {v.x, v.y, v.z, v.w};
      for (int j = 0; j < 4; ++j)
        if (gc + j < outF) Y[(size_t)gr * outF + gc + j] = vs[j];
    }
  }
}

// ---------------- big GEMM (fine, outF%128==0): 128x128 tile, BK=32, 8x8/thread ----------------
// Wt uses skip-4 padded columns: col c -> c + 4*(c>>3). b128 bases stay 16B-aligned
// (group stride 48B), read bank-starts (12g)%32 cover each bank exactly 2x (free),
// row stride 196 (%32==4) keeps staging writes at 4-way like k_gemm2. K%32==0.
#define WIDX(c) ((c) + 4 * ((c) >> 3))
__global__ __launch_bounds__(256) void k_gemm3(const float* __restrict__ X,
                                               const float* __restrict__ W,
                                               const float* __restrict__ bias,
                                               float* __restrict__ Y,
                                               int nrows, int K, int outF, int act) {
  __shared__ float Xt[32][132];
  __shared__ float Wt[32][196];
  int row0 = blockIdx.x * 128;
  int col0 = blockIdx.y * 128;
  int tid = threadIdx.x;
  int tc = (tid & 15) * 8;            // output cols tc..tc+7
  int wbase = 12 * (tid & 15);        // WIDX(tc)
  int tr = (tid >> 4) * 8;
  float acc[8][8] = {};
  for (int kk = 0; kk < K; kk += 32) {
#pragma unroll
    for (int i = 0; i < 4; ++i) {
      int f = tid + 256 * i;          // 0..1023
      int r = f >> 3;                 // 0..127
      int kq = f & 7;
      int kb = kq * 4;
      int gr = row0 + r;
      float4 v = make_float4(0.f, 0.f, 0.f, 0.f);
      if (gr < nrows) v = *(const float4*)&X[(size_t)gr * K + kk + kq * 4];
      Xt[kb][r] = v.x; Xt[kb + 1][r] = v.y; Xt[kb + 2][r] = v.z; Xt[kb + 3][r] = v.w;
      int gc = col0 + r;              // outF%128==0 and gridy=outF/128 -> gc < outF
      float4 w = *(const float4*)&W[(size_t)gc * K + kk + kq * 4];
      int wi = WIDX(r);
      Wt[kb][wi] = w.x; Wt[kb + 1][wi] = w.y; Wt[kb + 2][wi] = w.z; Wt[kb + 3][wi] = w.w;
    }
    __syncthreads();
#pragma unroll 4
    for (int k = 0; k < 32; ++k) {
      float4 xa = *(const float4*)&Xt[k][tr];
      float4 xb = *(const float4*)&Xt[k][tr + 4];
      float4 wa = *(const float4*)&Wt[k][wbase];
      float4 wb = *(const float4*)&Wt[k][wbase + 4];
      float xs[8] = {xa.x, xa.y, xa.z, xa.w, xb.x, xb.y, xb.z, xb.w};
      float ws[8] = {wa.x, wa.y, wa.z, wa.w, wb.x, wb.y, wb.z, wb.w};
#pragma unroll
      for (int i = 0; i < 8; ++i)
#pragma unroll
        for (int j = 0; j < 8; ++j) acc[i][j] += xs[i] * ws[j];
    }
    __syncthreads();
  }
#pragma unroll
  for (int i = 0; i < 8; ++i) {
    int gr = row0 + tr + i;
    if (gr >= nrows) continue;
#pragma unroll
    for (int h = 0; h < 2; ++h) {
      int gc = col0 + tc + h * 4;
      float4 v;
      v.x = acc[i][h * 4 + 0]; v.y = acc[i][h * 4 + 1];
      v.z = acc[i][h * 4 + 2]; v.w = acc[i][h * 4 + 3];
      if (bias) { v.x += bias[gc]; v.y += bias[gc + 1]; v.z += bias[gc + 2]; v.w += bias[gc + 3]; }
      if (act) { v.x = eluf(v.x); v.y = eluf(v.y); v.z = eluf(v.z); v.w = eluf(v.w); }
      *(float4*)&Y[(size_t)gr * outF + gc] = v;
    }
  }
}

// ---------------- fine aggregation F=64: wave/dst, 8x ILP, vectorized index loads ----------------
__global__ __launch_bounds__(256) void k_agg_fine64(
    const int* __restrict__ rowptr, const int* __restrict__ csrc, const float* __restrict__ cnorm,
    const float* __restrict__ h, const float* __restrict__ dinv, const float* __restrict__ bias,
    float* __restrict__ out, int n) {
  int w = blockIdx.x * 4 + (threadIdx.x >> 6);
  if (w >= n) return;
  int lane = threadIdx.x & 63;
  int start = rowptr[w], end = rowptr[w + 1];
  float acc = 0.f;
  int e = start;
  while (e < end && (e & 3)) { acc += cnorm[e] * h[(size_t)csrc[e] * 64 + lane]; ++e; }
  for (; e + 7 < end; e += 8) {
    int4 ia = *(const int4*)&csrc[e];
    int4 ib = *(const int4*)&csrc[e + 4];
    float4 na = *(const float4*)&cnorm[e];
    float4 nb = *(const float4*)&cnorm[e + 4];
    float v0 = h[(size_t)ia.x * 64 + lane];
    float v1 = h[(size_t)ia.y * 64 + lane];
    float v2 = h[(size_t)ia.z * 64 + lane];
    float v3 = h[(size_t)ia.w * 64 + lane];
    float v4 = h[(size_t)ib.x * 64 + lane];
    float v5 = h[(size_t)ib.y * 64 + lane];
    float v6 = h[(size_t)ib.z * 64 + lane];
    float v7 = h[(size_t)ib.w * 64 + lane];
    acc += na.x * v0 + na.y * v1 + na.z * v2 + na.w * v3 +
           nb.x * v4 + nb.y * v5 + nb.z * v6 + nb.w * v7;
  }
  for (; e < end; ++e) acc += cnorm[e] * h[(size_t)csrc[e] * 64 + lane];
  float dd = dinv[w]; dd *= dd;
  out[(size_t)w * 64 + lane] = eluf(acc + dd * h[(size_t)w * 64 + lane] + bias[lane]);
}

// ---------------- fine aggregation F=128, HALF-COLUMN pass ----------------
__global__ __launch_bounds__(256) void k_agg_fine128h(
    const int* __restrict__ rowptr, const int* __restrict__ csrc, const float* __restrict__ cnorm,
    const float* __restrict__ h, const float* __restrict__ dinv,
    float* __restrict__ out, int n, int half) {
  int w = blockIdx.x * 4 + (threadIdx.x >> 6);
  if (w >= n) return;
  int lane = threadIdx.x & 63;
  const float* hh = h + half * 64 + lane;
  int start = rowptr[w], end = rowptr[w + 1];
  float acc = 0.f;
  int e = start;
  while (e < end && (e & 3)) { acc += cnorm[e] * hh[(size_t)csrc[e] * 128]; ++e; }
  for (; e + 7 < end; e += 8) {
    int4 ia = *(const int4*)&csrc[e];
    int4 ib = *(const int4*)&csrc[e + 4];
    float4 na = *(const float4*)&cnorm[e];
    float4 nb = *(const float4*)&cnorm[e + 4];
    float v0 = hh[(size_t)ia.x * 128];
    float v1 = hh[(size_t)ia.y * 128];
    float v2 = hh[(size_t)ia.z * 128];
    float v3 = hh[(size_t)ia.w * 128];
    float v4 = hh[(size_t)ib.x * 128];
    float v5 = hh[(size_t)ib.y * 128];
    float v6 = hh[(size_t)ib.z * 128];
    float v7 = hh[(size_t)ib.w * 128];
    acc += na.x * v0 + na.y * v1 + na.z * v2 + na.w * v3 +
           nb.x * v4 + nb.y * v5 + nb.z * v6 + nb.w * v7;
  }
  for (; e < end; ++e) acc += cnorm[e] * hh[(size_t)csrc[e] * 128];
  float dd = dinv[w]; dd *= dd;
  out[(size_t)w * 128 + half * 64 + lane] = acc + dd * hh[(size_t)w * 128];
}

// ---------------- coarse aggregation (block/dst), per-wave quarter + 4x ILP ----------------
__global__ __launch_bounds__(256) void k_agg_coarse(int F,
    const int* __restrict__ rowptr, const int* __restrict__ csrc, const float* __restrict__ cnorm,
    const float* __restrict__ h, const float* __restrict__ dinv, const float* __restrict__ bias,
    float* __restrict__ out, int act) {
  int d = blockIdx.x;
  int lane = threadIdx.x & 63, wv = threadIdx.x >> 6;
  int start = rowptr[d], end = rowptr[d + 1];
  int cnt = end - start;
  int per = (cnt + 3) >> 2;
  int wbeg = start + wv * per;
  int wend = wbeg + per; if (wend > end) wend = end;
  float acc0 = 0.f, acc1 = 0.f;
  int e = wbeg;
  for (; e + 3 < wend; e += 4) {
    int s0 = csrc[e], s1 = csrc[e + 1], s2 = csrc[e + 2], s3 = csrc[e + 3];
    float n0 = cnorm[e], n1 = cnorm[e + 1], n2 = cnorm[e + 2], n3 = cnorm[e + 3];
    if (lane < F)
      acc0 += n0 * h[(size_t)s0 * F + lane] + n1 * h[(size_t)s1 * F + lane] +
              n2 * h[(size_t)s2 * F + lane] + n3 * h[(size_t)s3 * F + lane];
    if (lane + 64 < F)
      acc1 += n0 * h[(size_t)s0 * F + lane + 64] + n1 * h[(size_t)s1 * F + lane + 64] +
              n2 * h[(size_t)s2 * F + lane + 64] + n3 * h[(size_t)s3 * F + lane + 64];
  }
  for (; e < wend; ++e) {
    int s = csrc[e];
    float nm = cnorm[e];
    if (lane < F) acc0 += nm * h[(size_t)s * F + lane];
    if (lane + 64 < F) acc1 += nm * h[(size_t)s * F + lane + 64];
  }
  __shared__ float red[4][128];
  if (lane < F) red[wv][lane] = acc0;
  if (lane + 64 < F) red[wv][lane + 64] = acc1;
  __syncthreads();
  if (wv == 0) {
#pragma unroll 2
    for (int j = 0; j < 2; ++j) {
      int c = lane + j * 64;
      if (c < F) {
        float v = red[0][c] + red[1][c] + red[2][c] + red[3][c];
        float dd = dinv[d] * dinv[d];
        v += dd * h[(size_t)d * F + c] + bias[c];
        if (act) v = eluf(v);
        out[(size_t)d * F + c] = v;
      }
    }
  }
}

// ---------------- coarse agg + FC1 + FC2 ----------------
__global__ __launch_bounds__(256) void k_agg_coarse_fc2(int F,
    const int* __restrict__ rowptr, const int* __restrict__ csrc, const float* __restrict__ cnorm,
    const float* __restrict__ h, const float* __restrict__ dinv, const float* __restrict__ bias,
    const float* __restrict__ Wf, const float* __restrict__ bf, int outF2,
    const float* __restrict__ W2, int outF3,
    float* __restrict__ out) {
  int d = blockIdx.x;
  int lane = threadIdx.x & 63, wv = threadIdx.x >> 6;
  int start = rowptr[d], end = rowptr[d + 1];
  int cnt = end - start;
  int per = (cnt + 3) >> 2;
  int wbeg = start + wv * per;
  int wend = wbeg + per; if (wend > end) wend = end;
  float acc0 = 0.f, acc1 = 0.f;
  int e = wbeg;
  for (; e + 3 < wend; e += 4) {
    int s0 = csrc[e], s1 = csrc[e + 1], s2 = csrc[e + 2], s3 = csrc[e + 3];
    float n0 = cnorm[e], n1 = cnorm[e + 1], n2 = cnorm[e + 2], n3 = cnorm[e + 3];
    if (lane < F)
      acc0 += n0 * h[(size_t)s0 * F + lane] + n1 * h[(size_t)s1 * F + lane] +
              n2 * h[(size_t)s2 * F + lane] + n3 * h[(size_t)s3 * F + lane];
    if (lane + 64 < F)
      acc1 += n0 * h[(size_t)s0 * F + lane + 64] + n1 * h[(size_t)s1 * F + lane + 64] +
              n2 * h[(size_t)s2 * F + lane + 64] + n3 * h[(size_t)s3 * F + lane + 64];
  }
  for (; e < wend; ++e) {
    int s = csrc[e];
    float nm = cnorm[e];
    if (lane < F) acc0 += nm * h[(size_t)s * F + lane];
    if (lane + 64 < F) acc1 += nm * h[(size_t)s * F + lane + 64];
  }
  __shared__ float red[4][128];
  __shared__ __align__(16) float a_sh[128];
  __shared__ __align__(16) float z2_sh[96];
  if (lane < F) red[wv][lane] = acc0;
  if (lane + 64 < F) red[wv][lane + 64] = acc1;
  __syncthreads();
  if (wv == 0) {
#pragma unroll 2
    for (int j = 0; j < 2; ++j) {
      int c = lane + j * 64;
      if (c < F) {
        float v = red[0][c] + red[1][c] + red[2][c] + red[3][c];
        float dd = dinv[d] * dinv[d];
        a_sh[c] = eluf(v + dd * h[(size_t)d * F + c] + bias[c]);
      }
    }
  }
  __syncthreads();
  int j = threadIdx.x;
  if (j < outF2) {
    const float4* wr = (const float4*)(Wf + (size_t)j * F);
    const float4* ar = (const float4*)a_sh;
    float s = bf[j];
    for (int c = 0; c < (F >> 2); ++c) {
      float4 wv4 = wr[c];
      float4 av = ar[c];
      s += wv4.x * av.x + wv4.y * av.y + wv4.z * av.z + wv4.w * av.w;
    }
    z2_sh[j] = eluf(s);
  }
  __syncthreads();
  int m = threadIdx.x;
  if (m < outF3) {
    const float4* wr = (const float4*)(W2 + (size_t)m * outF2);
    const float4* zr = (const float4*)z2_sh;
    float s = 0.f;
    for (int c = 0; c < (outF2 >> 2); ++c) {
      float4 wv4 = wr[c];
      float4 zv = zr[c];
      s += wv4.x * zv.x + wv4.y * zv.y + wv4.z * zv.z + wv4.w * zv.w;
    }
    out[(size_t)d * outF3 + m] = s;
  }
}

// ---------------- instance-norm stats ----------------
__global__ __launch_bounds__(256) void k_chanstats(const float* __restrict__ x, int n,
                                                   float* __restrict__ s, float* __restrict__ s2) {
  int ch = threadIdx.x;
  float a = 0.f, b = 0.f;
  for (int r = blockIdx.x; r < n; r += gridDim.x) {
    float v = x[(size_t)r * 256 + ch];
    a += v;
    b += v * v;
  }
  atomicAdd(&s[ch], a);
  atomicAdd(&s2[ch], b);
}

// ---------------- fused mu/rstd + normalize + cluster pool + first coarse GEMM ----------------
__global__ __launch_bounds__(256) void k_pool_gemm(const float* __restrict__ x,
                                                   const int* __restrict__ rowptr,
                                                   const int* __restrict__ nodes,
                                                   const float* __restrict__ sS,
                                                   const float* __restrict__ sS2,
                                                   float ninv,
                                                   const float* __restrict__ W,  // [128][256]
                                                   float* __restrict__ t) {      // [CC][128]
  int c = blockIdx.x;
  int ch = threadIdx.x;
  __shared__ __align__(16) float a_sh[256];
  float mu = sS[ch] * ninv;
  float var = sS2[ch] * ninv - mu * mu;
  float rstd = rsqrtf(var + 1e-5f);
  int start = rowptr[c], end = rowptr[c + 1];
  float s = 0.f;
  int i = start;
  for (; i + 3 < end; i += 4) {
    float v0 = x[(size_t)nodes[i] * 256 + ch];
    float v1 = x[(size_t)nodes[i + 1] * 256 + ch];
    float v2 = x[(size_t)nodes[i + 2] * 256 + ch];
    float v3 = x[(size_t)nodes[i + 3] * 256 + ch];
    s += v0 + v1 + v2 + v3;
  }
  for (; i < end; ++i) s += x[(size_t)nodes[i] * 256 + ch];
  int cnt = end - start; if (cnt < 1) cnt = 1;
  a_sh[ch] = (s / (float)cnt - mu) * rstd;
  __syncthreads();
  int j = threadIdx.x;
  if (j < 128) {
    const float4* wr = (const float4*)(W + (size_t)j * 256);
    const float4* ar = (const float4*)a_sh;
    float acc = 0.f;
#pragma unroll 8
    for (int q = 0; q < 64; ++q) {
      float4 w4 = wr[q];
      float4 av = ar[q];
      acc += w4.x * av.x + w4.y * av.y + w4.z * av.z + w4.w * av.w;
    }
    t[(size_t)c * 128 + j] = acc;
  }
}

// ---------------- o_feat = W_fcO @ g ----------------
__global__ __launch_bounds__(256) void k_matvec(const float* __restrict__ W,
                                                const float* __restrict__ g,
                                                float* __restrict__ out, int M, int K) {
  __shared__ __align__(16) float gs[2560];
  for (int i = threadIdx.x; i < K; i += 256) gs[i] = g[i];
  __syncthreads();
  int lane = threadIdx.x & 63, wv = threadIdx.x >> 6;
#pragma unroll
  for (int rr = 0; rr < 4; ++rr) {
    int row = blockIdx.x * 16 + wv * 4 + rr;
    if (row >= M) break;
    const float4* Wr = (const float4*)(W + (size_t)row * K);
    float acc = 0.f;
#pragma unroll
    for (int it = 0; it < 10; ++it) {
      float4 w4 = Wr[it * 64 + lane];
      float4 g4 = *(const float4*)&gs[it * 256 + lane * 4];
      acc += w4.x * g4.x + w4.y * g4.y + w4.z * g4.z + w4.w * g4.w;
    }
#pragma unroll
    for (int off = 32; off; off >>= 1) acc += __shfl_down(acc, off, 64);
    if (lane == 0) out[row] = acc;
  }
}

// ==================================================================================
extern "C" void kernel_launch(void* const* d_in, const int* in_sizes, int n_in,
                              void* d_out, int out_size, void* d_ws, size_t ws_size,
                              hipStream_t stream) {
  const float* x     = (const float*)d_in[0];
  const float* W_G1  = (const float*)d_in[1];
  const float* b_G1  = (const float*)d_in[2];
  const float* Wf_G1 = (const float*)d_in[3];
  const float* bf_G1 = (const float*)d_in[4];
  const float* W_G2  = (const float*)d_in[5];
  const float* b_G2  = (const float*)d_in[6];
  const float* Wf_G2 = (const float*)d_in[7];
  const float* bf_G2 = (const float*)d_in[8];
  const float* W_L1  = (const float*)d_in[9];
  const float* b_L1  = (const float*)d_in[10];
  const float* Wf_L1 = (const float*)d_in[11];
  const float* bf_L1 = (const float*)d_in[12];
  const float* W_L2  = (const float*)d_in[13];
  const float* b_L2  = (const float*)d_in[14];
  const float* Wf_L2 = (const float*)d_in[15];
  const float* bf_L2 = (const float*)d_in[16];
  const float* W_M1  = (const float*)d_in[17];
  const float* b_M1  = (const float*)d_in[18];
  const float* Wf_M1 = (const float*)d_in[19];
  const float* bf_M1 = (const float*)d_in[20];
  const float* W_O1  = (const float*)d_in[21];
  const float* b_O1  = (const float*)d_in[22];
  const float* W_fcO = (const float*)d_in[23];
  const int* edge    = (const int*)d_in[24];
  const int* cluster = (const int*)d_in[25];
  const int* cedge   = (const int*)d_in[27];

  const int E  = in_sizes[24] / 2;
  const int Ec = in_sizes[27] / 2;

  char* ws = (char*)d_ws;
  size_t off = 0;
  auto alloc = [&](size_t bytes) -> void* {
    void* p = ws + off;
    off = (off + bytes + 255) & ~(size_t)255;
    return p;
  };

  float* bufA = (float*)alloc((size_t)NN * 256 * 4);
  float* bufB = (float*)alloc((size_t)NN * 256 * 4);
  float* bufC = (float*)alloc((size_t)NN * 256 * 4);
  float* zA   = (float*)alloc((size_t)CC * 256 * 4);
  float* zB   = (float*)alloc((size_t)CC * 256 * 4);
  float* dinvF = (float*)alloc((size_t)NN * 4);
  float* dinvC = (float*)alloc((size_t)CC * 4);
  int* rowF  = (int*)alloc((size_t)(NN + 1) * 4);
  int* rowC  = (int*)alloc((size_t)(CC + 1) * 4);
  int* rowCl = (int*)alloc((size_t)(CC + 1) * 4);
  int* csrcF = (int*)alloc((size_t)E * 4);
  float* cnormF = (float*)alloc((size_t)E * 4);
  int* csrcC = (int*)alloc((size_t)Ec * 4);
  float* cnormC = (float*)alloc((size_t)Ec * 4);
  int* cnodes = (int*)alloc((size_t)NN * 4);
  // ---- contiguous zero region ----
  size_t zoff = off;
  int* degF  = (int*)alloc((size_t)NN * 4);
  int* fillF = (int*)alloc((size_t)NN * 4);
  int* degC  = (int*)alloc((size_t)CC * 4);
  int* fillC = (int*)alloc((size_t)CC * 4);
  int* degCl = (int*)alloc((size_t)CC * 4);
  int* fillCl = (int*)alloc((size_t)CC * 4);
  float* chanS  = (float*)alloc(256 * 4);
  float* chanS2 = (float*)alloc(256 * 4);
  size_t zbytes = off - zoff;

  float* g_out = (float*)d_out;          // [2560] g_feat
  float* o_out = (float*)d_out + 2560;   // [60000] o_feat

  auto cdiv = [](int a, int b) { return (a + b - 1) / b; };

  k_zero<<<cdiv((int)(zbytes / 16), 256), 256, 0, stream>>>((float4*)(ws + zoff), (int)(zbytes / 16));

  // ---- fused CSR build: counts -> scans(+dinv) -> scatters ----
  k_count3<<<cdiv(E + Ec + NN, 256), 256, 0, stream>>>(edge + E, E, degF,
                                                       cedge + Ec, Ec, degC,
                                                       cluster, NN, degCl);
  k_scan3<<<3, 1024, 0, stream>>>(degF, NN, rowF, dinvF,
                                  degC, CC, rowC, dinvC,
                                  degCl, CC, rowCl);
  k_scatter3<<<cdiv(E + Ec + NN, 256), 256, 0, stream>>>(
      edge, E, rowF, fillF, dinvF, csrcF, cnormF,
      cedge, Ec, rowC, fillC, dinvC, csrcC, cnormC,
      cluster, NN, rowCl, fillCl, cnodes);

  // ---- fine pipeline ----
  k_gemm2<<<dim3(cdiv(NN, 128), 1), 256, 0, stream>>>(x, W_G1, nullptr, bufA, NN, 128, 64, 0);
  k_agg_fine64<<<NN / 4, 256, 0, stream>>>(rowF, csrcF, cnormF, bufA, dinvF, b_G1, bufC, NN);
  k_gemm3<<<dim3(cdiv(NN, 128), 1), 256, 0, stream>>>(bufC, Wf_G1, bf_G1, bufA, NN, 64, 128, 1);
  k_agg_fine128h<<<NN / 4, 256, 0, stream>>>(rowF, csrcF, cnormF, bufA, dinvF, bufC, NN, 0);
  k_agg_fine128h<<<NN / 4, 256, 0, stream>>>(rowF, csrcF, cnormF, bufA, dinvF, bufC, NN, 1);
  k_gemm3<<<dim3(cdiv(NN, 128), 2), 256, 0, stream>>>(bufC, W_G2, b_G2, bufB, NN, 128, 256, 1);
  k_gemm3<<<dim3(cdiv(NN, 128), 2), 256, 0, stream>>>(bufB, Wf_G2, bf_G2, bufA, NN, 256, 256, 1);

  // ---- instance norm stats + fused pool + first coarse GEMM ----
  k_chanstats<<<256, 256, 0, stream>>>(bufA, NN, chanS, chanS2);
  k_pool_gemm<<<CC, 256, 0, stream>>>(bufA, rowCl, cnodes, chanS, chanS2, 1.f / (float)NN,
                                      W_L1, zA);

  // ---- coarse pipeline (agg + FC + next-GCN-linear fused) ----
  k_agg_coarse_fc2<<<CC, 256, 0, stream>>>(128, rowC, csrcC, cnormC, zA, dinvC, b_L1,
                                           Wf_L1, bf_L1, 96, W_L2, 64, zB);
  k_agg_coarse_fc2<<<CC, 256, 0, stream>>>(64, rowC, csrcC, cnormC, zB, dinvC, b_L2,
                                           Wf_L2, bf_L2, 32, W_M1, 16, zA);
  k_agg_coarse_fc2<<<CC, 256, 0, stream>>>(16, rowC, csrcC, cnormC, zA, dinvC, b_M1,
                                           Wf_M1, bf_M1, 8, W_O1, 5, zB);
  k_agg_coarse<<<CC, 256, 0, stream>>>(5, rowC, csrcC, cnormC, zB, dinvC, b_O1, g_out, 0);

  // ---- o_feat = W_fcO @ g_feat ----
  k_matvec<<<cdiv(3 * NN, 16), 256, 0, stream>>>(W_fcO, g_out, o_out, 3 * NN, 2560);
}

// Round 11
// 548.103 us; speedup vs baseline: 1.0444x; 1.0444x over previous
//
#include <hip/hip_runtime.h>
#include <math.h>

#define NN 20000
#define CC 512

__device__ __forceinline__ float eluf(float x) { return x > 0.f ? x : __expf(x) - 1.f; }

// ---------------- zero ----------------
__global__ void k_zero(float4* __restrict__ p, int n4) {
  int i = blockIdx.x * blockDim.x + threadIdx.x;
  if (i < n4) p[i] = make_float4(0.f, 0.f, 0.f, 0.f);
}

// ---------------- fused CSR counting (fine dst, coarse dst, cluster) ----------------
__global__ void k_count3(const int* __restrict__ dstF, int nF, int* __restrict__ cF,
                         const int* __restrict__ dstC, int nC, int* __restrict__ cC,
                         const int* __restrict__ clus, int nK, int* __restrict__ cK) {
  int i = blockIdx.x * blockDim.x + threadIdx.x;
  if (i < nF) { atomicAdd(&cF[dstF[i]], 1); return; }
  i -= nF;
  if (i < nC) { atomicAdd(&cC[dstC[i]], 1); return; }
  i -= nC;
  if (i < nK) atomicAdd(&cK[clus[i]], 1);
}

// ---------------- 3-array scan (block per array) + optional dinv ----------------
__global__ __launch_bounds__(1024) void k_scan3(
    const int* __restrict__ c0, int n0, int* __restrict__ r0, float* __restrict__ d0,
    const int* __restrict__ c1, int n1, int* __restrict__ r1, float* __restrict__ d1,
    const int* __restrict__ c2, int n2, int* __restrict__ r2) {
  const int* counts; int n; int* rowptr; float* dinv;
  if (blockIdx.x == 0) { counts = c0; n = n0; rowptr = r0; dinv = d0; }
  else if (blockIdx.x == 1) { counts = c1; n = n1; rowptr = r1; dinv = d1; }
  else { counts = c2; n = n2; rowptr = r2; dinv = nullptr; }
  __shared__ int part[1024];
  int tid = threadIdx.x;
  int chunk = (n + 1023) >> 10;
  int beg = tid * chunk;
  int fin = beg + chunk; if (fin > n) fin = n;
  int s = 0;
  for (int i = beg; i < fin; ++i) {
    int c = counts[i];
    s += c;
    if (dinv) dinv[i] = rsqrtf((float)(c + 1));  // +1 self-loop
  }
  part[tid] = s;
  __syncthreads();
  for (int off = 1; off < 1024; off <<= 1) {
    int v = (tid >= off) ? part[tid - off] : 0;
    __syncthreads();
    part[tid] += v;
    __syncthreads();
  }
  int base = (tid == 0) ? 0 : part[tid - 1];
  for (int i = beg; i < fin; ++i) { rowptr[i] = base; base += counts[i]; }
  if (tid == 1023) rowptr[n] = part[1023];
}

// ---------------- fused scatter (fine edges, coarse edges, cluster nodes) ----------------
__global__ void k_scatter3(
    const int* __restrict__ edgeF, int EF, const int* __restrict__ rowF, int* __restrict__ fillF,
    const float* __restrict__ dinvF, int* __restrict__ csrcF, float* __restrict__ cnormF,
    const int* __restrict__ edgeC, int EC, const int* __restrict__ rowC, int* __restrict__ fillC,
    const float* __restrict__ dinvC, int* __restrict__ csrcC, float* __restrict__ cnormC,
    const int* __restrict__ clus, int NK, const int* __restrict__ rowK, int* __restrict__ fillK,
    int* __restrict__ cnodes) {
  int i = blockIdx.x * blockDim.x + threadIdx.x;
  if (i < EF) {
    int d = edgeF[EF + i];
    int pos = rowF[d] + atomicAdd(&fillF[d], 1);
    int s = edgeF[i];
    csrcF[pos] = s;
    cnormF[pos] = dinvF[s] * dinvF[d];
    return;
  }
  i -= EF;
  if (i < EC) {
    int d = edgeC[EC + i];
    int pos = rowC[d] + atomicAdd(&fillC[d], 1);
    int s = edgeC[i];
    csrcC[pos] = s;
    cnormC[pos] = dinvC[s] * dinvC[d];
    return;
  }
  i -= EC;
  if (i < NK) {
    int d = clus[i];
    int pos = rowK[d] + atomicAdd(&fillK[d], 1);
    cnodes[pos] = i;
  }
}

// ---------------- big GEMM (fine stages): 128x64 tile, BK=32, 8x4/thread, float4 staging ----------------
__global__ __launch_bounds__(256) void k_gemm2(const float* __restrict__ X,
                                               const float* __restrict__ W,
                                               const float* __restrict__ bias,
                                               float* __restrict__ Y,
                                               int nrows, int K, int outF, int act) {
  __shared__ float Xt[32][132];
  __shared__ float Wt[32][68];
  int row0 = blockIdx.x * 128;
  int col0 = blockIdx.y * 64;
  int tid = threadIdx.x;
  int tc = (tid & 15) * 4;
  int tr = (tid >> 4) * 8;
  float acc[8][4] = {};
  for (int kk = 0; kk < K; kk += 32) {
#pragma unroll
    for (int i = 0; i < 4; ++i) {
      int f = tid + 256 * i;        // 0..1023
      int r = f >> 3;               // 0..127
      int kq = f & 7;
      int gr = row0 + r;
      float4 v = make_float4(0.f, 0.f, 0.f, 0.f);
      if (gr < nrows) v = *(const float4*)&X[(size_t)gr * K + kk + kq * 4];
      int kb = kq * 4;
      Xt[kb][r] = v.x; Xt[kb + 1][r] = v.y; Xt[kb + 2][r] = v.z; Xt[kb + 3][r] = v.w;
    }
#pragma unroll
    for (int i = 0; i < 2; ++i) {
      int f = tid + 256 * i;        // 0..511
      int c = f >> 3;               // 0..63
      int kq = f & 7;
      int gc = col0 + c;
      float4 v = make_float4(0.f, 0.f, 0.f, 0.f);
      if (gc < outF) v = *(const float4*)&W[(size_t)gc * K + kk + kq * 4];
      int kb = kq * 4;
      Wt[kb][c] = v.x; Wt[kb + 1][c] = v.y; Wt[kb + 2][c] = v.z; Wt[kb + 3][c] = v.w;
    }
    __syncthreads();
#pragma unroll 8
    for (int k = 0; k < 32; ++k) {
      float4 w = *(const float4*)&Wt[k][tc];
      float4 xa = *(const float4*)&Xt[k][tr];
      float4 xb = *(const float4*)&Xt[k][tr + 4];
      float xs[8] = {xa.x, xa.y, xa.z, xa.w, xb.x, xb.y, xb.z, xb.w};
      float ws4[4] = {w.x, w.y, w.z, w.w};
#pragma unroll
      for (int i = 0; i < 8; ++i)
#pragma unroll
        for (int j = 0; j < 4; ++j) acc[i][j] += xs[i] * ws4[j];
    }
    __syncthreads();
  }
#pragma unroll
  for (int i = 0; i < 8; ++i) {
    int gr = row0 + tr + i;
    if (gr >= nrows) continue;
    int gc = col0 + tc;
    float4 v;
    v.x = acc[i][0]; v.y = acc[i][1]; v.z = acc[i][2]; v.w = acc[i][3];
    if (bias) { v.x += bias[gc]; v.y += bias[gc + 1]; v.z += bias[gc + 2]; v.w += bias[gc + 3]; }
    if (act) { v.x = eluf(v.x); v.y = eluf(v.y); v.z = eluf(v.z); v.w = eluf(v.w); }
    if (gc + 3 < outF) {
      *(float4*)&Y[(size_t)gr * outF + gc] = v;
    } else {
      float vs[4] = {v.x, v.y, v.z, v.w};
      for (int j = 0; j < 4; ++j)
        if (gc + j < outF) Y[(size_t)gr * outF + gc + j] = vs[j];
    }
  }
}

// ---------------- fine aggregation F=64: wave/dst, 8x ILP, vectorized index loads ----------------
__global__ __launch_bounds__(256) void k_agg_fine64(
    const int* __restrict__ rowptr, const int* __restrict__ csrc, const float* __restrict__ cnorm,
    const float* __restrict__ h, const float* __restrict__ dinv, const float* __restrict__ bias,
    float* __restrict__ out, int n) {
  int w = blockIdx.x * 4 + (threadIdx.x >> 6);
  if (w >= n) return;
  int lane = threadIdx.x & 63;
  int start = rowptr[w], end = rowptr[w + 1];
  float acc = 0.f;
  int e = start;
  while (e < end && (e & 3)) { acc += cnorm[e] * h[(size_t)csrc[e] * 64 + lane]; ++e; }
  for (; e + 7 < end; e += 8) {
    int4 ia = *(const int4*)&csrc[e];
    int4 ib = *(const int4*)&csrc[e + 4];
    float4 na = *(const float4*)&cnorm[e];
    float4 nb = *(const float4*)&cnorm[e + 4];
    float v0 = h[(size_t)ia.x * 64 + lane];
    float v1 = h[(size_t)ia.y * 64 + lane];
    float v2 = h[(size_t)ia.z * 64 + lane];
    float v3 = h[(size_t)ia.w * 64 + lane];
    float v4 = h[(size_t)ib.x * 64 + lane];
    float v5 = h[(size_t)ib.y * 64 + lane];
    float v6 = h[(size_t)ib.z * 64 + lane];
    float v7 = h[(size_t)ib.w * 64 + lane];
    acc += na.x * v0 + na.y * v1 + na.z * v2 + na.w * v3 +
           nb.x * v4 + nb.y * v5 + nb.z * v6 + nb.w * v7;
  }
  for (; e < end; ++e) acc += cnorm[e] * h[(size_t)csrc[e] * 64 + lane];
  float dd = dinv[w]; dd *= dd;
  out[(size_t)w * 64 + lane] = eluf(acc + dd * h[(size_t)w * 64 + lane] + bias[lane]);
}

// ---------------- fine aggregation F=128, HALF-COLUMN pass ----------------
__global__ __launch_bounds__(256) void k_agg_fine128h(
    const int* __restrict__ rowptr, const int* __restrict__ csrc, const float* __restrict__ cnorm,
    const float* __restrict__ h, const float* __restrict__ dinv,
    float* __restrict__ out, int n, int half) {
  int w = blockIdx.x * 4 + (threadIdx.x >> 6);
  if (w >= n) return;
  int lane = threadIdx.x & 63;
  const float* hh = h + half * 64 + lane;
  int start = rowptr[w], end = rowptr[w + 1];
  float acc = 0.f;
  int e = start;
  while (e < end && (e & 3)) { acc += cnorm[e] * hh[(size_t)csrc[e] * 128]; ++e; }
  for (; e + 7 < end; e += 8) {
    int4 ia = *(const int4*)&csrc[e];
    int4 ib = *(const int4*)&csrc[e + 4];
    float4 na = *(const float4*)&cnorm[e];
    float4 nb = *(const float4*)&cnorm[e + 4];
    float v0 = hh[(size_t)ia.x * 128];
    float v1 = hh[(size_t)ia.y * 128];
    float v2 = hh[(size_t)ia.z * 128];
    float v3 = hh[(size_t)ia.w * 128];
    float v4 = hh[(size_t)ib.x * 128];
    float v5 = hh[(size_t)ib.y * 128];
    float v6 = hh[(size_t)ib.z * 128];
    float v7 = hh[(size_t)ib.w * 128];
    acc += na.x * v0 + na.y * v1 + na.z * v2 + na.w * v3 +
           nb.x * v4 + nb.y * v5 + nb.z * v6 + nb.w * v7;
  }
  for (; e < end; ++e) acc += cnorm[e] * hh[(size_t)csrc[e] * 128];
  float dd = dinv[w]; dd *= dd;
  out[(size_t)w * 128 + half * 64 + lane] = acc + dd * hh[(size_t)w * 128];
}

// ---------------- coarse aggregation (block/dst), per-wave quarter + 4x ILP ----------------
__global__ __launch_bounds__(256) void k_agg_coarse(int F,
    const int* __restrict__ rowptr, const int* __restrict__ csrc, const float* __restrict__ cnorm,
    const float* __restrict__ h, const float* __restrict__ dinv, const float* __restrict__ bias,
    float* __restrict__ out, int act) {
  int d = blockIdx.x;
  int lane = threadIdx.x & 63, wv = threadIdx.x >> 6;
  int start = rowptr[d], end = rowptr[d + 1];
  int cnt = end - start;
  int per = (cnt + 3) >> 2;
  int wbeg = start + wv * per;
  int wend = wbeg + per; if (wend > end) wend = end;
  float acc0 = 0.f, acc1 = 0.f;
  int e = wbeg;
  for (; e + 3 < wend; e += 4) {
    int s0 = csrc[e], s1 = csrc[e + 1], s2 = csrc[e + 2], s3 = csrc[e + 3];
    float n0 = cnorm[e], n1 = cnorm[e + 1], n2 = cnorm[e + 2], n3 = cnorm[e + 3];
    if (lane < F)
      acc0 += n0 * h[(size_t)s0 * F + lane] + n1 * h[(size_t)s1 * F + lane] +
              n2 * h[(size_t)s2 * F + lane] + n3 * h[(size_t)s3 * F + lane];
    if (lane + 64 < F)
      acc1 += n0 * h[(size_t)s0 * F + lane + 64] + n1 * h[(size_t)s1 * F + lane + 64] +
              n2 * h[(size_t)s2 * F + lane + 64] + n3 * h[(size_t)s3 * F + lane + 64];
  }
  for (; e < wend; ++e) {
    int s = csrc[e];
    float nm = cnorm[e];
    if (lane < F) acc0 += nm * h[(size_t)s * F + lane];
    if (lane + 64 < F) acc1 += nm * h[(size_t)s * F + lane + 64];
  }
  __shared__ float red[4][128];
  if (lane < F) red[wv][lane] = acc0;
  if (lane + 64 < F) red[wv][lane + 64] = acc1;
  __syncthreads();
  if (wv == 0) {
#pragma unroll 2
    for (int j = 0; j < 2; ++j) {
      int c = lane + j * 64;
      if (c < F) {
        float v = red[0][c] + red[1][c] + red[2][c] + red[3][c];
        float dd = dinv[d] * dinv[d];
        v += dd * h[(size_t)d * F + c] + bias[c];
        if (act) v = eluf(v);
        out[(size_t)d * F + c] = v;
      }
    }
  }
}

// ---------------- coarse agg + FC1 + FC2 ----------------
__global__ __launch_bounds__(256) void k_agg_coarse_fc2(int F,
    const int* __restrict__ rowptr, const int* __restrict__ csrc, const float* __restrict__ cnorm,
    const float* __restrict__ h, const float* __restrict__ dinv, const float* __restrict__ bias,
    const float* __restrict__ Wf, const float* __restrict__ bf, int outF2,
    const float* __restrict__ W2, int outF3,
    float* __restrict__ out) {
  int d = blockIdx.x;
  int lane = threadIdx.x & 63, wv = threadIdx.x >> 6;
  int start = rowptr[d], end = rowptr[d + 1];
  int cnt = end - start;
  int per = (cnt + 3) >> 2;
  int wbeg = start + wv * per;
  int wend = wbeg + per; if (wend > end) wend = end;
  float acc0 = 0.f, acc1 = 0.f;
  int e = wbeg;
  for (; e + 3 < wend; e += 4) {
    int s0 = csrc[e], s1 = csrc[e + 1], s2 = csrc[e + 2], s3 = csrc[e + 3];
    float n0 = cnorm[e], n1 = cnorm[e + 1], n2 = cnorm[e + 2], n3 = cnorm[e + 3];
    if (lane < F)
      acc0 += n0 * h[(size_t)s0 * F + lane] + n1 * h[(size_t)s1 * F + lane] +
              n2 * h[(size_t)s2 * F + lane] + n3 * h[(size_t)s3 * F + lane];
    if (lane + 64 < F)
      acc1 += n0 * h[(size_t)s0 * F + lane + 64] + n1 * h[(size_t)s1 * F + lane + 64] +
              n2 * h[(size_t)s2 * F + lane + 64] + n3 * h[(size_t)s3 * F + lane + 64];
  }
  for (; e < wend; ++e) {
    int s = csrc[e];
    float nm = cnorm[e];
    if (lane < F) acc0 += nm * h[(size_t)s * F + lane];
    if (lane + 64 < F) acc1 += nm * h[(size_t)s * F + lane + 64];
  }
  __shared__ float red[4][128];
  __shared__ __align__(16) float a_sh[128];
  __shared__ __align__(16) float z2_sh[96];
  if (lane < F) red[wv][lane] = acc0;
  if (lane + 64 < F) red[wv][lane + 64] = acc1;
  __syncthreads();
  if (wv == 0) {
#pragma unroll 2
    for (int j = 0; j < 2; ++j) {
      int c = lane + j * 64;
      if (c < F) {
        float v = red[0][c] + red[1][c] + red[2][c] + red[3][c];
        float dd = dinv[d] * dinv[d];
        a_sh[c] = eluf(v + dd * h[(size_t)d * F + c] + bias[c]);
      }
    }
  }
  __syncthreads();
  int j = threadIdx.x;
  if (j < outF2) {
    const float4* wr = (const float4*)(Wf + (size_t)j * F);
    const float4* ar = (const float4*)a_sh;
    float s = bf[j];
    for (int c = 0; c < (F >> 2); ++c) {
      float4 wv4 = wr[c];
      float4 av = ar[c];
      s += wv4.x * av.x + wv4.y * av.y + wv4.z * av.z + wv4.w * av.w;
    }
    z2_sh[j] = eluf(s);
  }
  __syncthreads();
  int m = threadIdx.x;
  if (m < outF3) {
    const float4* wr = (const float4*)(W2 + (size_t)m * outF2);
    const float4* zr = (const float4*)z2_sh;
    float s = 0.f;
    for (int c = 0; c < (outF2 >> 2); ++c) {
      float4 wv4 = wr[c];
      float4 zv = zr[c];
      s += wv4.x * zv.x + wv4.y * zv.y + wv4.z * zv.z + wv4.w * zv.w;
    }
    out[(size_t)d * outF3 + m] = s;
  }
}

// ---------------- instance-norm stats ----------------
__global__ __launch_bounds__(256) void k_chanstats(const float* __restrict__ x, int n,
                                                   float* __restrict__ s, float* __restrict__ s2) {
  int ch = threadIdx.x;
  float a = 0.f, b = 0.f;
  for (int r = blockIdx.x; r < n; r += gridDim.x) {
    float v = x[(size_t)r * 256 + ch];
    a += v;
    b += v * v;
  }
  atomicAdd(&s[ch], a);
  atomicAdd(&s2[ch], b);
}

// ---------------- fused mu/rstd + normalize + cluster pool + first coarse GEMM ----------------
__global__ __launch_bounds__(256) void k_pool_gemm(const float* __restrict__ x,
                                                   const int* __restrict__ rowptr,
                                                   const int* __restrict__ nodes,
                                                   const float* __restrict__ sS,
                                                   const float* __restrict__ sS2,
                                                   float ninv,
                                                   const float* __restrict__ W,  // [128][256]
                                                   float* __restrict__ t) {      // [CC][128]
  int c = blockIdx.x;
  int ch = threadIdx.x;
  __shared__ __align__(16) float a_sh[256];
  float mu = sS[ch] * ninv;
  float var = sS2[ch] * ninv - mu * mu;
  float rstd = rsqrtf(var + 1e-5f);
  int start = rowptr[c], end = rowptr[c + 1];
  float s = 0.f;
  int i = start;
  for (; i + 3 < end; i += 4) {
    float v0 = x[(size_t)nodes[i] * 256 + ch];
    float v1 = x[(size_t)nodes[i + 1] * 256 + ch];
    float v2 = x[(size_t)nodes[i + 2] * 256 + ch];
    float v3 = x[(size_t)nodes[i + 3] * 256 + ch];
    s += v0 + v1 + v2 + v3;
  }
  for (; i < end; ++i) s += x[(size_t)nodes[i] * 256 + ch];
  int cnt = end - start; if (cnt < 1) cnt = 1;
  a_sh[ch] = (s / (float)cnt - mu) * rstd;
  __syncthreads();
  int j = threadIdx.x;
  if (j < 128) {
    const float4* wr = (const float4*)(W + (size_t)j * 256);
    const float4* ar = (const float4*)a_sh;
    float acc = 0.f;
#pragma unroll 8
    for (int q = 0; q < 64; ++q) {
      float4 w4 = wr[q];
      float4 av = ar[q];
      acc += w4.x * av.x + w4.y * av.y + w4.z * av.z + w4.w * av.w;
    }
    t[(size_t)c * 128 + j] = acc;
  }
}

// ---------------- o_feat = W_fcO @ g ----------------
__global__ __launch_bounds__(256) void k_matvec(const float* __restrict__ W,
                                                const float* __restrict__ g,
                                                float* __restrict__ out, int M, int K) {
  __shared__ __align__(16) float gs[2560];
  for (int i = threadIdx.x; i < K; i += 256) gs[i] = g[i];
  __syncthreads();
  int lane = threadIdx.x & 63, wv = threadIdx.x >> 6;
#pragma unroll
  for (int rr = 0; rr < 4; ++rr) {
    int row = blockIdx.x * 16 + wv * 4 + rr;
    if (row >= M) break;
    const float4* Wr = (const float4*)(W + (size_t)row * K);
    float acc = 0.f;
#pragma unroll
    for (int it = 0; it < 10; ++it) {
      float4 w4 = Wr[it * 64 + lane];
      float4 g4 = *(const float4*)&gs[it * 256 + lane * 4];
      acc += w4.x * g4.x + w4.y * g4.y + w4.z * g4.z + w4.w * g4.w;
    }
#pragma unroll
    for (int off = 32; off; off >>= 1) acc += __shfl_down(acc, off, 64);
    if (lane == 0) out[row] = acc;
  }
}

// ==================================================================================
extern "C" void kernel_launch(void* const* d_in, const int* in_sizes, int n_in,
                              void* d_out, int out_size, void* d_ws, size_t ws_size,
                              hipStream_t stream) {
  const float* x     = (const float*)d_in[0];
  const float* W_G1  = (const float*)d_in[1];
  const float* b_G1  = (const float*)d_in[2];
  const float* Wf_G1 = (const float*)d_in[3];
  const float* bf_G1 = (const float*)d_in[4];
  const float* W_G2  = (const float*)d_in[5];
  const float* b_G2  = (const float*)d_in[6];
  const float* Wf_G2 = (const float*)d_in[7];
  const float* bf_G2 = (const float*)d_in[8];
  const float* W_L1  = (const float*)d_in[9];
  const float* b_L1  = (const float*)d_in[10];
  const float* Wf_L1 = (const float*)d_in[11];
  const float* bf_L1 = (const float*)d_in[12];
  const float* W_L2  = (const float*)d_in[13];
  const float* b_L2  = (const float*)d_in[14];
  const float* Wf_L2 = (const float*)d_in[15];
  const float* bf_L2 = (const float*)d_in[16];
  const float* W_M1  = (const float*)d_in[17];
  const float* b_M1  = (const float*)d_in[18];
  const float* Wf_M1 = (const float*)d_in[19];
  const float* bf_M1 = (const float*)d_in[20];
  const float* W_O1  = (const float*)d_in[21];
  const float* b_O1  = (const float*)d_in[22];
  const float* W_fcO = (const float*)d_in[23];
  const int* edge    = (const int*)d_in[24];
  const int* cluster = (const int*)d_in[25];
  const int* cedge   = (const int*)d_in[27];

  const int E  = in_sizes[24] / 2;
  const int Ec = in_sizes[27] / 2;

  char* ws = (char*)d_ws;
  size_t off = 0;
  auto alloc = [&](size_t bytes) -> void* {
    void* p = ws + off;
    off = (off + bytes + 255) & ~(size_t)255;
    return p;
  };

  float* bufA = (float*)alloc((size_t)NN * 256 * 4);
  float* bufB = (float*)alloc((size_t)NN * 256 * 4);
  float* bufC = (float*)alloc((size_t)NN * 256 * 4);
  float* zA   = (float*)alloc((size_t)CC * 256 * 4);
  float* zB   = (float*)alloc((size_t)CC * 256 * 4);
  float* dinvF = (float*)alloc((size_t)NN * 4);
  float* dinvC = (float*)alloc((size_t)CC * 4);
  int* rowF  = (int*)alloc((size_t)(NN + 1) * 4);
  int* rowC  = (int*)alloc((size_t)(CC + 1) * 4);
  int* rowCl = (int*)alloc((size_t)(CC + 1) * 4);
  int* csrcF = (int*)alloc((size_t)E * 4);
  float* cnormF = (float*)alloc((size_t)E * 4);
  int* csrcC = (int*)alloc((size_t)Ec * 4);
  float* cnormC = (float*)alloc((size_t)Ec * 4);
  int* cnodes = (int*)alloc((size_t)NN * 4);
  // ---- contiguous zero region ----
  size_t zoff = off;
  int* degF  = (int*)alloc((size_t)NN * 4);
  int* fillF = (int*)alloc((size_t)NN * 4);
  int* degC  = (int*)alloc((size_t)CC * 4);
  int* fillC = (int*)alloc((size_t)CC * 4);
  int* degCl = (int*)alloc((size_t)CC * 4);
  int* fillCl = (int*)alloc((size_t)CC * 4);
  float* chanS  = (float*)alloc(256 * 4);
  float* chanS2 = (float*)alloc(256 * 4);
  size_t zbytes = off - zoff;

  float* g_out = (float*)d_out;          // [2560] g_feat
  float* o_out = (float*)d_out + 2560;   // [60000] o_feat

  auto cdiv = [](int a, int b) { return (a + b - 1) / b; };

  k_zero<<<cdiv((int)(zbytes / 16), 256), 256, 0, stream>>>((float4*)(ws + zoff), (int)(zbytes / 16));

  // ---- fused CSR build: counts -> scans(+dinv) -> scatters ----
  k_count3<<<cdiv(E + Ec + NN, 256), 256, 0, stream>>>(edge + E, E, degF,
                                                       cedge + Ec, Ec, degC,
                                                       cluster, NN, degCl);
  k_scan3<<<3, 1024, 0, stream>>>(degF, NN, rowF, dinvF,
                                  degC, CC, rowC, dinvC,
                                  degCl, CC, rowCl);
  k_scatter3<<<cdiv(E + Ec + NN, 256), 256, 0, stream>>>(
      edge, E, rowF, fillF, dinvF, csrcF, cnormF,
      cedge, Ec, rowC, fillC, dinvC, csrcC, cnormC,
      cluster, NN, rowCl, fillCl, cnodes);

  // ---- fine pipeline ----
  k_gemm2<<<dim3(cdiv(NN, 128), 1), 256, 0, stream>>>(x, W_G1, nullptr, bufA, NN, 128, 64, 0);
  k_agg_fine64<<<NN / 4, 256, 0, stream>>>(rowF, csrcF, cnormF, bufA, dinvF, b_G1, bufC, NN);
  k_gemm2<<<dim3(cdiv(NN, 128), 2), 256, 0, stream>>>(bufC, Wf_G1, bf_G1, bufA, NN, 64, 128, 1);
  k_agg_fine128h<<<NN / 4, 256, 0, stream>>>(rowF, csrcF, cnormF, bufA, dinvF, bufC, NN, 0);
  k_agg_fine128h<<<NN / 4, 256, 0, stream>>>(rowF, csrcF, cnormF, bufA, dinvF, bufC, NN, 1);
  k_gemm2<<<dim3(cdiv(NN, 128), 4), 256, 0, stream>>>(bufC, W_G2, b_G2, bufB, NN, 128, 256, 1);
  k_gemm2<<<dim3(cdiv(NN, 128), 4), 256, 0, stream>>>(bufB, Wf_G2, bf_G2, bufA, NN, 256, 256, 1);

  // ---- instance norm stats + fused pool + first coarse GEMM ----
  k_chanstats<<<256, 256, 0, stream>>>(bufA, NN, chanS, chanS2);
  k_pool_gemm<<<CC, 256, 0, stream>>>(bufA, rowCl, cnodes, chanS, chanS2, 1.f / (float)NN,
                                      W_L1, zA);

  // ---- coarse pipeline (agg + FC + next-GCN-linear fused) ----
  k_agg_coarse_fc2<<<CC, 256, 0, stream>>>(128, rowC, csrcC, cnormC, zA, dinvC, b_L1,
                                           Wf_L1, bf_L1, 96, W_L2, 64, zB);
  k_agg_coarse_fc2<<<CC, 256, 0, stream>>>(64, rowC, csrcC, cnormC, zB, dinvC, b_L2,
                                           Wf_L2, bf_L2, 32, W_M1, 16, zA);
  k_agg_coarse_fc2<<<CC, 256, 0, stream>>>(16, rowC, csrcC, cnormC, zA, dinvC, b_M1,
                                           Wf_M1, bf_M1, 8, W_O1, 5, zB);
  k_agg_coarse<<<CC, 256, 0, stream>>>(5, rowC, csrcC, cnormC, zB, dinvC, b_O1, g_out, 0);

  // ---- o_feat = W_fcO @ g_feat ----
  k_matvec<<<cdiv(3 * NN, 16), 256, 0, stream>>>(W_fcO, g_out, o_out, 3 * NN, 2560);
}